// Round 5
// baseline (361.724 us; speedup 1.0000x reference)
//
#include <hip/hip_runtime.h>
#include <stdint.h>

#define NN 50000
#define NE 800000
#define CAST_B 6250   // NN*128/4/256 exactly
#define CVTW_B 512    // 8*16384/256
#define EPB 8192      // edges per hist/scatter block
#define HIST_B 98     // ceil(NE/EPB)
#define NBK 196       // coarse buckets: dst>>8 (49999>>8 = 195)
#define FUSE_B 782    // ceil(NN/64) blocks for fused agg+gemm

typedef short short8 __attribute__((ext_vector_type(8)));
typedef float f32x4 __attribute__((ext_vector_type(4)));
typedef unsigned int uint;
typedef unsigned short ushort;

__device__ __forceinline__ uint rne_bf16(float f) {
    uint x = __float_as_uint(f);
    return (x + 0x7FFFu + ((x >> 16) & 1u)) >> 16;  // round-to-nearest-even
}
__device__ __forceinline__ float bf_lo(uint d) { return __uint_as_float(d << 16); }
__device__ __forceinline__ float bf_hi(uint d) { return __uint_as_float(d & 0xFFFF0000u); }

// int64 edge_index => int32 view is [lo,hi,lo,hi,...] with hi==0 (vals<50000).
// For int32 data these words are random node ids; P(all 4 zero) ~ 2e-19.
__device__ __forceinline__ int ei_is64(const int* __restrict__ ei) {
    return (ei[1] | ei[3] | ei[5] | ei[7]) == 0;
}

struct Ptrs8 { const float* p[8]; };

// -------- prep: x-cast | W-cast (fragment-major) | edge pack + coarse hist ---
// R0/R1 lesson: 800k global atomicAdds are serviced memory-side (~18 Gops/s,
// 25.6MB write-through) regardless of scope -> 2-level LDS-atomic bucket sort.
// R4 lesson (-53us): W cast into MFMA-FRAGMENT-MAJOR order so GEMM B loads are
// `base + lane*16B` coalesced 1KB wave loads. Within matrix m:
// idx = ((k0i*8 + t)*64 + lane)*8+e holds W[r=t*16+(lane&15)][c=k0i*32+(lane>>4)*8+e].
__global__ __launch_bounds__(256) void k_prep(
    const float* __restrict__ x, ushort* __restrict__ xbf, Ptrs8 ps,
    ushort* __restrict__ wbf, const int* __restrict__ ei,
    uint* __restrict__ ebuf, int* __restrict__ hcnt) {
    __shared__ int hs[NBK];
    int b = blockIdx.x;
    if (b < CAST_B) {                       // cast x -> bf16 row-major
        int i = b * 256 + threadIdx.x;
        float4 v = ((const float4*)x)[i];
        uint2 o;
        o.x = rne_bf16(v.x) | (rne_bf16(v.y) << 16);
        o.y = rne_bf16(v.z) | (rne_bf16(v.w) << 16);
        ((uint2*)xbf)[i] = o;
    } else if (b < CAST_B + CVTW_B) {       // cast 8 W matrices, frag-major
        int idx = (b - CAST_B) * 256 + threadIdx.x;
        int m = idx >> 14;
        int o14 = idx & 16383;
        int k0i = (o14 >> 12) & 3;
        int t = (o14 >> 9) & 7;
        int lane6 = (o14 >> 3) & 63;
        int e = o14 & 7;
        int r = t * 16 + (lane6 & 15);
        int c = k0i * 32 + (lane6 >> 4) * 8 + e;
        wbf[idx] = (ushort)rne_bf16(ps.p[m][r * 128 + c]);
    } else {                                // pack edges + coarse hist
        int hb = b - CAST_B - CVTW_B;
        int t = threadIdx.x;
        for (int i = t; i < NBK; i += 256) hs[i] = 0;
        __syncthreads();
        int base = hb * EPB;
        int is64 = ei_is64(ei);
        for (int i = 0; i < EPB; i += 256) {
            int e = base + i + t;
            if (e < NE) {
                int sv = is64 ? ei[2 * e] : ei[e];
                int dv = is64 ? ei[2 * NE + 2 * e] : ei[NE + e];
                ebuf[e] = ((uint)dv << 16) | (uint)sv;
                atomicAdd(&hs[dv >> 8], 1);
            }
        }
        __syncthreads();
        for (int i = t; i < NBK; i += 256) hcnt[hb * NBK + i] = hs[i];
    }
}

// single block: bucket totals -> exclusive bases -> per-(block,bucket) offsets
__global__ __launch_bounds__(256) void k_scan1(const int* __restrict__ hcnt,
                                               int* __restrict__ hoff,
                                               int* __restrict__ bb,
                                               int* __restrict__ row_ptr) {
    __shared__ int s[256];
    int t = threadIdx.x;
    int tot = 0;
    if (t < NBK)
        for (int b = 0; b < HIST_B; b++) tot += hcnt[b * NBK + t];
    s[t] = tot;
    __syncthreads();
    for (int off = 1; off < 256; off <<= 1) {  // inclusive scan
        int v = s[t];
        int a = (t >= off) ? s[t - off] : 0;
        __syncthreads();
        s[t] = v + a;
        __syncthreads();
    }
    if (t < NBK) {
        int base = (t == 0) ? 0 : s[t - 1];  // exclusive
        bb[t] = base;
        int run = base;
        for (int b = 0; b < HIST_B; b++) {
            hoff[b * NBK + t] = run;
            run += hcnt[b * NBK + t];
        }
    }
    if (t == 0) { bb[NBK] = NE; row_ptr[NN] = NE; }
}

// coarse scatter: LDS rank counters, writes land in ~170B runs per bucket
__global__ __launch_bounds__(256) void k_scatter1(const uint* __restrict__ ebuf,
                                                  const int* __restrict__ hoff,
                                                  uint* __restrict__ ebuf2) {
    __shared__ int pos[NBK];
    int hb = blockIdx.x, t = threadIdx.x;
    for (int i = t; i < NBK; i += 256) pos[i] = hoff[hb * NBK + i];
    __syncthreads();
    int base = hb * EPB;
    for (int i = 0; i < EPB; i += 256) {
        int e = base + i + t;
        if (e < NE) {
            uint pk = ebuf[e];
            int idx = atomicAdd(&pos[pk >> 24], 1);
            ebuf2[idx] = pk;
        }
    }
}

// per-bucket counting sort: one block per 256-node bucket (~4k edges), two
// passes over its global range; emits col (src) and row_ptr directly.
__global__ __launch_bounds__(1024) void k_sort2(const uint* __restrict__ ebuf2,
                                                const int* __restrict__ bb,
                                                int* __restrict__ row_ptr,
                                                ushort* __restrict__ col) {
    __shared__ int hist[256];
    __shared__ int pos[256];
    int k = blockIdx.x, t = threadIdx.x;
    int beg = bb[k], end = bb[k + 1];
    if (t < 256) hist[t] = 0;
    __syncthreads();
    for (int j = beg + t; j < end; j += 1024)
        atomicAdd(&hist[(ebuf2[j] >> 16) & 255], 1);
    __syncthreads();
    for (int off = 1; off < 256; off <<= 1) {  // inclusive scan (1024-thr safe)
        int v = 0;
        if (t < 256) { v = hist[t]; if (t >= off) v += hist[t - off]; }
        __syncthreads();
        if (t < 256) hist[t] = v;
        __syncthreads();
    }
    if (t < 256) {
        int ex = (t == 0) ? 0 : hist[t - 1];
        pos[t] = beg + ex;
        int node = k * 256 + t;
        if (node < NN) row_ptr[node] = beg + ex;
    }
    __syncthreads();
    for (int j = beg + t; j < end; j += 1024) {
        uint pk = ebuf2[j];
        int idx = atomicAdd(&pos[(pk >> 16) & 255], 1);
        col[idx] = (ushort)(pk & 0xFFFFu);
    }
}

// -------- fused mean-aggregation + MFMA GEMM (R5) ----------------------------
// Block = 64 output rows, 4 waves. Phase 1: each wave runs the measured-best
// agg3 body (bit-identical) for its 16 nodes, landing packed bf16 means in LDS
// ([64][68] uint pad -> A-frag ds_read_b128 is 2-way aliased = free). Phase 2:
// 16-row/wave MFMA GEMM, mean half from LDS, h half from global, frag-major W.
// Kills the meanbf HBM roundtrip (25.6MB/layer) + 4 launches; MFMA overlaps
// gathers via co-resident blocks. 782 blocks x 4 waves ~ 12 waves/CU: enough
// outstanding gathers (~96) for the ~33 lines/CU needed at 5.1 TB/s.
// R2 lesson stands: do NOT feature-split the gathers (2x regression).
__global__ __launch_bounds__(256) void k_fused(
    const ushort* __restrict__ h, const int* __restrict__ row_ptr,
    const ushort* __restrict__ col, const ushort* __restrict__ Wlb,
    const ushort* __restrict__ Wrb, const float* __restrict__ bias,
    float* __restrict__ outf, ushort* __restrict__ outb, int relu) {
    __shared__ uint smean[64 * 68];  // row-major, 68-uint pitch (+4 pad)
    const int wid = threadIdx.x >> 6;
    const int lane = threadIdx.x & 63;
    const int m0 = blockIdx.x * 64;
    const uint* hp = (const uint*)h;  // row = 64 uints (128 bf16)

    // ---- phase 1: aggregate 16 nodes per wave (agg3 body, LDS output) ----
    for (int ni = 0; ni < 16; ni++) {
        int rl = wid * 16 + ni;
        int node = m0 + rl;
        if (node < NN) {
            int beg = row_ptr[node], end = row_ptr[node + 1];
            float a0 = 0.f, a1 = 0.f;
            for (int b = beg; b < end; b += 64) {  // one iter for deg <= 64
                int n = min(64, end - b);
                int c = (int)col[b + min(lane, n - 1)];
                for (int j0 = 0; j0 < n; j0 += 8) {
#pragma unroll
                    for (int j = 0; j < 8; j++) {
                        int jj = j0 + j;                   // wave-uniform
                        int s = __shfl(c, min(jj, n - 1)); // uniform broadcast
                        uint v = hp[s * 64 + lane];        // coalesced 256B row
                        float m = (jj < n) ? 1.f : 0.f;
                        a0 = fmaf(m, bf_lo(v), a0);
                        a1 = fmaf(m, bf_hi(v), a1);
                    }
                }
            }
            float r = 1.0f / (float)max(end - beg, 1);
            smean[rl * 68 + lane] = rne_bf16(a0 * r) | (rne_bf16(a1 * r) << 16);
        } else {
            smean[rl * 68 + lane] = 0;  // clean rows for the MFMA below
        }
    }
    __syncthreads();

    // ---- phase 2: 16 rows per wave: out = mean@Wl^T + h@Wr^T + b (+ReLU) ----
    const int l15 = lane & 15;
    const int quad = lane >> 4;
    f32x4 acc[8];
#pragma unroll
    for (int t = 0; t < 8; t++) acc[t] = (f32x4){0.f, 0.f, 0.f, 0.f};

    int arow = min(m0 + wid * 16 + l15, NN - 1);  // clamp; stores guarded
    const ushort* Arh = h + (size_t)arow * 128 + quad * 8;
    const uint* Alds = &smean[(wid * 16 + l15) * 68 + quad * 4];

#pragma unroll
    for (int half = 0; half < 2; half++) {
        const ushort* W = half ? Wrb : Wlb;
#pragma unroll
        for (int k0 = 0; k0 < 128; k0 += 32) {
            short8 a = half ? *(const short8*)(Arh + k0)
                            : *(const short8*)(Alds + (k0 >> 1));
            const ushort* Wk = W + ((k0 >> 5) * 8) * 512 + lane * 8;
#pragma unroll
            for (int t = 0; t < 8; t++) {
                short8 b = *(const short8*)(Wk + t * 512);
                acc[t] = __builtin_amdgcn_mfma_f32_16x16x32_bf16(a, b, acc[t], 0, 0, 0);
            }
        }
    }

    float bb[8];
#pragma unroll
    for (int t = 0; t < 8; t++) bb[t] = bias[t * 16 + l15];

#pragma unroll
    for (int r = 0; r < 4; r++) {
        int row = m0 + wid * 16 + quad * 4 + r;  // C/D: row = quad*4 + reg
        if (row < NN) {
#pragma unroll
            for (int t = 0; t < 8; t++) {
                float v = acc[t][r] + bb[t];
                if (relu) v = fmaxf(v, 0.f);
                if (outb) outb[(size_t)row * 128 + t * 16 + l15] = (ushort)rne_bf16(v);
                else outf[(size_t)row * 128 + t * 16 + l15] = v;
            }
        }
    }
}

extern "C" void kernel_launch(void* const* d_in, const int* in_sizes, int n_in,
                              void* d_out, int out_size, void* d_ws, size_t ws_size,
                              hipStream_t stream) {
    const float* x = (const float*)d_in[0];
    const int* ei = (const int*)d_in[1];
    const float* Wl[4] = {(const float*)d_in[2], (const float*)d_in[5],
                          (const float*)d_in[8], (const float*)d_in[11]};
    const float* bl[4] = {(const float*)d_in[3], (const float*)d_in[6],
                          (const float*)d_in[9], (const float*)d_in[12]};
    const float* Wr[4] = {(const float*)d_in[4], (const float*)d_in[7],
                          (const float*)d_in[10], (const float*)d_in[13]};
    float* out = (float*)d_out;

    char* p = (char*)d_ws;
    auto take = [&](size_t bytes) -> char* {
        char* r = p;
        p += (bytes + 255) & ~(size_t)255;
        return r;
    };
    uint* ebuf = (uint*)take((size_t)NE * 4);
    uint* ebuf2 = (uint*)take((size_t)NE * 4);
    int* hcnt = (int*)take((size_t)HIST_B * NBK * 4);
    int* hoff = (int*)take((size_t)HIST_B * NBK * 4);
    int* bb = (int*)take((NBK + 1) * 4);
    int* row_ptr = (int*)take((NN + 1) * 4);
    ushort* col = (ushort*)take((size_t)NE * 2 + 256);  // +pad
    ushort* xbf = (ushort*)take((size_t)NN * 128 * 2);
    ushort* h1 = (ushort*)take((size_t)NN * 128 * 2);
    ushort* h2 = (ushort*)take((size_t)NN * 128 * 2);
    ushort* wbf = (ushort*)take(8 * 16384 * 2);

    Ptrs8 ps;
    ps.p[0] = Wl[0]; ps.p[1] = Wr[0]; ps.p[2] = Wl[1]; ps.p[3] = Wr[1];
    ps.p[4] = Wl[2]; ps.p[5] = Wr[2]; ps.p[6] = Wl[3]; ps.p[7] = Wr[3];

    // CSR via 2-level bucket sort: no global atomics, no memset, no fill.
    k_prep<<<CAST_B + CVTW_B + HIST_B, 256, 0, stream>>>(x, xbf, ps, wbf, ei,
                                                         ebuf, hcnt);
    k_scan1<<<1, 256, 0, stream>>>(hcnt, hoff, bb, row_ptr);
    k_scatter1<<<HIST_B, 256, 0, stream>>>(ebuf, hoff, ebuf2);
    k_sort2<<<NBK, 1024, 0, stream>>>(ebuf2, bb, row_ptr, col);

    const ushort* h = xbf;
    ushort* houts[4] = {h1, h2, h1, nullptr};  // final layer -> fp32 d_out
    for (int l = 0; l < 4; l++) {
        k_fused<<<FUSE_B, 256, 0, stream>>>(
            h, row_ptr, col, wbf + (size_t)(2 * l) * 16384,
            wbf + (size_t)(2 * l + 1) * 16384, bl[l], out, houts[l],
            l == 0 ? 1 : 0);
        h = houts[l];
    }
}

// Round 6
// 360.305 us; speedup vs baseline: 1.0039x; 1.0039x over previous
//
#include <hip/hip_runtime.h>
#include <stdint.h>

#define NN 50000
#define NE 800000
#define CAST_B 6250   // NN*128/4/256 exactly
#define CVTW_B 512    // 8*16384/256
#define EPB 8192      // edges per hist/scatter block
#define HIST_B 98     // ceil(NE/EPB)
#define NBK 196       // coarse buckets: dst>>8 (49999>>8 = 195)
#define FUSE_B 782    // ceil(NN/64) blocks for fused agg+gemm

typedef short short8 __attribute__((ext_vector_type(8)));
typedef float f32x4 __attribute__((ext_vector_type(4)));
typedef unsigned int uint;
typedef unsigned short ushort;

__device__ __forceinline__ uint rne_bf16(float f) {
    uint x = __float_as_uint(f);
    return (x + 0x7FFFu + ((x >> 16) & 1u)) >> 16;  // round-to-nearest-even
}
__device__ __forceinline__ float bf_lo(uint d) { return __uint_as_float(d << 16); }
__device__ __forceinline__ float bf_hi(uint d) { return __uint_as_float(d & 0xFFFF0000u); }

// int64 edge_index => int32 view is [lo,hi,lo,hi,...] with hi==0 (vals<50000).
// For int32 data these words are random node ids; P(all 4 zero) ~ 2e-19.
__device__ __forceinline__ int ei_is64(const int* __restrict__ ei) {
    return (ei[1] | ei[3] | ei[5] | ei[7]) == 0;
}

struct Ptrs8 { const float* p[8]; };

// -------- prep: x-cast | W-cast (fragment-major) | edge pack + coarse hist ---
// R0/R1 lesson: 800k global atomicAdds are serviced memory-side (~18 Gops/s,
// 25.6MB write-through) regardless of scope -> 2-level LDS-atomic bucket sort.
// R4 lesson (-53us): W cast into MFMA-FRAGMENT-MAJOR order so GEMM B loads are
// `base + lane*16B` coalesced 1KB wave loads. Within matrix m:
// idx = ((k0i*8 + t)*64 + lane)*8+e holds W[r=t*16+(lane&15)][c=k0i*32+(lane>>4)*8+e].
__global__ __launch_bounds__(256) void k_prep(
    const float* __restrict__ x, ushort* __restrict__ xbf, Ptrs8 ps,
    ushort* __restrict__ wbf, const int* __restrict__ ei,
    uint* __restrict__ ebuf, int* __restrict__ hcnt) {
    __shared__ int hs[NBK];
    int b = blockIdx.x;
    if (b < CAST_B) {                       // cast x -> bf16 row-major
        int i = b * 256 + threadIdx.x;
        float4 v = ((const float4*)x)[i];
        uint2 o;
        o.x = rne_bf16(v.x) | (rne_bf16(v.y) << 16);
        o.y = rne_bf16(v.z) | (rne_bf16(v.w) << 16);
        ((uint2*)xbf)[i] = o;
    } else if (b < CAST_B + CVTW_B) {       // cast 8 W matrices, frag-major
        int idx = (b - CAST_B) * 256 + threadIdx.x;
        int m = idx >> 14;
        int o14 = idx & 16383;
        int k0i = (o14 >> 12) & 3;
        int t = (o14 >> 9) & 7;
        int lane6 = (o14 >> 3) & 63;
        int e = o14 & 7;
        int r = t * 16 + (lane6 & 15);
        int c = k0i * 32 + (lane6 >> 4) * 8 + e;
        wbf[idx] = (ushort)rne_bf16(ps.p[m][r * 128 + c]);
    } else {                                // pack edges + coarse hist
        int hb = b - CAST_B - CVTW_B;
        int t = threadIdx.x;
        for (int i = t; i < NBK; i += 256) hs[i] = 0;
        __syncthreads();
        int base = hb * EPB;
        int is64 = ei_is64(ei);
        for (int i = 0; i < EPB; i += 256) {
            int e = base + i + t;
            if (e < NE) {
                int sv = is64 ? ei[2 * e] : ei[e];
                int dv = is64 ? ei[2 * NE + 2 * e] : ei[NE + e];
                ebuf[e] = ((uint)dv << 16) | (uint)sv;
                atomicAdd(&hs[dv >> 8], 1);
            }
        }
        __syncthreads();
        for (int i = t; i < NBK; i += 256) hcnt[hb * NBK + i] = hs[i];
    }
}

// single block: bucket totals -> exclusive bases -> per-(block,bucket) offsets
__global__ __launch_bounds__(256) void k_scan1(const int* __restrict__ hcnt,
                                               int* __restrict__ hoff,
                                               int* __restrict__ bb,
                                               int* __restrict__ row_ptr) {
    __shared__ int s[256];
    int t = threadIdx.x;
    int tot = 0;
    if (t < NBK)
        for (int b = 0; b < HIST_B; b++) tot += hcnt[b * NBK + t];
    s[t] = tot;
    __syncthreads();
    for (int off = 1; off < 256; off <<= 1) {  // inclusive scan
        int v = s[t];
        int a = (t >= off) ? s[t - off] : 0;
        __syncthreads();
        s[t] = v + a;
        __syncthreads();
    }
    if (t < NBK) {
        int base = (t == 0) ? 0 : s[t - 1];  // exclusive
        bb[t] = base;
        int run = base;
        for (int b = 0; b < HIST_B; b++) {
            hoff[b * NBK + t] = run;
            run += hcnt[b * NBK + t];
        }
    }
    if (t == 0) { bb[NBK] = NE; row_ptr[NN] = NE; }
}

// coarse scatter: LDS rank counters, writes land in ~170B runs per bucket
__global__ __launch_bounds__(256) void k_scatter1(const uint* __restrict__ ebuf,
                                                  const int* __restrict__ hoff,
                                                  uint* __restrict__ ebuf2) {
    __shared__ int pos[NBK];
    int hb = blockIdx.x, t = threadIdx.x;
    for (int i = t; i < NBK; i += 256) pos[i] = hoff[hb * NBK + i];
    __syncthreads();
    int base = hb * EPB;
    for (int i = 0; i < EPB; i += 256) {
        int e = base + i + t;
        if (e < NE) {
            uint pk = ebuf[e];
            int idx = atomicAdd(&pos[pk >> 24], 1);
            ebuf2[idx] = pk;
        }
    }
}

// per-bucket counting sort: one block per 256-node bucket (~4k edges), two
// passes over its global range; emits col (src) and row_ptr directly.
__global__ __launch_bounds__(1024) void k_sort2(const uint* __restrict__ ebuf2,
                                                const int* __restrict__ bb,
                                                int* __restrict__ row_ptr,
                                                ushort* __restrict__ col) {
    __shared__ int hist[256];
    __shared__ int pos[256];
    int k = blockIdx.x, t = threadIdx.x;
    int beg = bb[k], end = bb[k + 1];
    if (t < 256) hist[t] = 0;
    __syncthreads();
    for (int j = beg + t; j < end; j += 1024)
        atomicAdd(&hist[(ebuf2[j] >> 16) & 255], 1);
    __syncthreads();
    for (int off = 1; off < 256; off <<= 1) {  // inclusive scan (1024-thr safe)
        int v = 0;
        if (t < 256) { v = hist[t]; if (t >= off) v += hist[t - off]; }
        __syncthreads();
        if (t < 256) hist[t] = v;
        __syncthreads();
    }
    if (t < 256) {
        int ex = (t == 0) ? 0 : hist[t - 1];
        pos[t] = beg + ex;
        int node = k * 256 + t;
        if (node < NN) row_ptr[node] = beg + ex;
    }
    __syncthreads();
    for (int j = beg + t; j < end; j += 1024) {
        uint pk = ebuf2[j];
        int idx = atomicAdd(&pos[(pk >> 16) & 255], 1);
        col[idx] = (ushort)(pk & 0xFFFFu);
    }
}

// -------- fused mean-aggregation + MFMA GEMM (R6: 16 waves/block) ------------
// R5 lesson: fusing at 4 waves/block (782-block grid) capped the chip at ~12
// waves/CU (Occupancy 25%) and the latency-bound gather phase lost 3x of its
// concurrency -> 60us/layer. Same fusion, 1024 threads/block: phase 1 gives
// each of 16 waves 4 nodes (49 waves/CU of work, 32 resident > agg3's 24);
// phase 2 splits the GEMM 4 rowgrp x 4 colgrp, acc[2] per wave (same MFMA
// total, 4x more parallel; h re-read by colgrps is L1/L2-served).
// Arithmetic is bit-identical to split agg3+gemm. R2 lesson stands: do NOT
// feature-split the gathers.
__global__ __launch_bounds__(1024) void k_fused(
    const ushort* __restrict__ h, const int* __restrict__ row_ptr,
    const ushort* __restrict__ col, const ushort* __restrict__ Wlb,
    const ushort* __restrict__ Wrb, const float* __restrict__ bias,
    float* __restrict__ outf, ushort* __restrict__ outb, int relu) {
    __shared__ uint smean[64 * 68];  // row-major, 68-uint pitch (+4 pad)
    const int wid = threadIdx.x >> 6;
    const int lane = threadIdx.x & 63;
    const int m0 = blockIdx.x * 64;
    const uint* hp = (const uint*)h;  // row = 64 uints (128 bf16)

    // ---- phase 1: each wave aggregates 4 nodes (agg3 body, LDS output) ----
#pragma unroll
    for (int ni = 0; ni < 4; ni++) {
        int rl = wid * 4 + ni;
        int node = m0 + rl;
        if (node < NN) {
            int beg = row_ptr[node], end = row_ptr[node + 1];
            float a0 = 0.f, a1 = 0.f;
            for (int b = beg; b < end; b += 64) {  // one iter for deg <= 64
                int n = min(64, end - b);
                int c = (int)col[b + min(lane, n - 1)];
                for (int j0 = 0; j0 < n; j0 += 8) {
#pragma unroll
                    for (int j = 0; j < 8; j++) {
                        int jj = j0 + j;                   // wave-uniform
                        int s = __shfl(c, min(jj, n - 1)); // uniform broadcast
                        uint v = hp[s * 64 + lane];        // coalesced 256B row
                        float m = (jj < n) ? 1.f : 0.f;
                        a0 = fmaf(m, bf_lo(v), a0);
                        a1 = fmaf(m, bf_hi(v), a1);
                    }
                }
            }
            float r = 1.0f / (float)max(end - beg, 1);
            smean[rl * 68 + lane] = rne_bf16(a0 * r) | (rne_bf16(a1 * r) << 16);
        } else {
            smean[rl * 68 + lane] = 0;  // clean rows for the MFMA below
        }
    }
    __syncthreads();

    // ---- phase 2: wave (rowgrp,colgrp): 16 rows x 32 cols of the output ----
    const int rowgrp = wid >> 2;   // 0..3
    const int colgrp = wid & 3;    // 0..3 -> t = colgrp*2 + {0,1}
    const int l15 = lane & 15;
    const int quad = lane >> 4;
    f32x4 acc[2];
    acc[0] = (f32x4){0.f, 0.f, 0.f, 0.f};
    acc[1] = (f32x4){0.f, 0.f, 0.f, 0.f};

    int arow = min(m0 + rowgrp * 16 + l15, NN - 1);  // clamp; stores guarded
    const ushort* Arh = h + (size_t)arow * 128 + quad * 8;
    const uint* Alds = &smean[(rowgrp * 16 + l15) * 68 + quad * 4];

#pragma unroll
    for (int half = 0; half < 2; half++) {
        const ushort* W = half ? Wrb : Wlb;
#pragma unroll
        for (int k0 = 0; k0 < 128; k0 += 32) {
            short8 a = half ? *(const short8*)(Arh + k0)
                            : *(const short8*)(Alds + (k0 >> 1));
            const ushort* Wk = W + ((k0 >> 5) * 8) * 512 + lane * 8;
#pragma unroll
            for (int tt = 0; tt < 2; tt++) {
                short8 b = *(const short8*)(Wk + (size_t)(colgrp * 2 + tt) * 512);
                acc[tt] = __builtin_amdgcn_mfma_f32_16x16x32_bf16(a, b, acc[tt], 0, 0, 0);
            }
        }
    }

    float bb2[2] = {bias[(colgrp * 2 + 0) * 16 + l15],
                    bias[(colgrp * 2 + 1) * 16 + l15]};

#pragma unroll
    for (int r = 0; r < 4; r++) {
        int row = m0 + rowgrp * 16 + quad * 4 + r;  // C/D: row = quad*4 + reg
        if (row < NN) {
#pragma unroll
            for (int tt = 0; tt < 2; tt++) {
                int cidx = (colgrp * 2 + tt) * 16 + l15;
                float v = acc[tt][r] + bb2[tt];
                if (relu) v = fmaxf(v, 0.f);
                if (outb) outb[(size_t)row * 128 + cidx] = (ushort)rne_bf16(v);
                else outf[(size_t)row * 128 + cidx] = v;
            }
        }
    }
}

extern "C" void kernel_launch(void* const* d_in, const int* in_sizes, int n_in,
                              void* d_out, int out_size, void* d_ws, size_t ws_size,
                              hipStream_t stream) {
    const float* x = (const float*)d_in[0];
    const int* ei = (const int*)d_in[1];
    const float* Wl[4] = {(const float*)d_in[2], (const float*)d_in[5],
                          (const float*)d_in[8], (const float*)d_in[11]};
    const float* bl[4] = {(const float*)d_in[3], (const float*)d_in[6],
                          (const float*)d_in[9], (const float*)d_in[12]};
    const float* Wr[4] = {(const float*)d_in[4], (const float*)d_in[7],
                          (const float*)d_in[10], (const float*)d_in[13]};
    float* out = (float*)d_out;

    char* p = (char*)d_ws;
    auto take = [&](size_t bytes) -> char* {
        char* r = p;
        p += (bytes + 255) & ~(size_t)255;
        return r;
    };
    uint* ebuf = (uint*)take((size_t)NE * 4);
    uint* ebuf2 = (uint*)take((size_t)NE * 4);
    int* hcnt = (int*)take((size_t)HIST_B * NBK * 4);
    int* hoff = (int*)take((size_t)HIST_B * NBK * 4);
    int* bb = (int*)take((NBK + 1) * 4);
    int* row_ptr = (int*)take((NN + 1) * 4);
    ushort* col = (ushort*)take((size_t)NE * 2 + 256);  // +pad
    ushort* xbf = (ushort*)take((size_t)NN * 128 * 2);
    ushort* h1 = (ushort*)take((size_t)NN * 128 * 2);
    ushort* h2 = (ushort*)take((size_t)NN * 128 * 2);
    ushort* wbf = (ushort*)take(8 * 16384 * 2);

    Ptrs8 ps;
    ps.p[0] = Wl[0]; ps.p[1] = Wr[0]; ps.p[2] = Wl[1]; ps.p[3] = Wr[1];
    ps.p[4] = Wl[2]; ps.p[5] = Wr[2]; ps.p[6] = Wl[3]; ps.p[7] = Wr[3];

    // CSR via 2-level bucket sort: no global atomics, no memset, no fill.
    k_prep<<<CAST_B + CVTW_B + HIST_B, 256, 0, stream>>>(x, xbf, ps, wbf, ei,
                                                         ebuf, hcnt);
    k_scan1<<<1, 256, 0, stream>>>(hcnt, hoff, bb, row_ptr);
    k_scatter1<<<HIST_B, 256, 0, stream>>>(ebuf, hoff, ebuf2);
    k_sort2<<<NBK, 1024, 0, stream>>>(ebuf2, bb, row_ptr, col);

    const ushort* h = xbf;
    ushort* houts[4] = {h1, h2, h1, nullptr};  // final layer -> fp32 d_out
    for (int l = 0; l < 4; l++) {
        k_fused<<<FUSE_B, 1024, 0, stream>>>(
            h, row_ptr, col, wbf + (size_t)(2 * l) * 16384,
            wbf + (size_t)(2 * l + 1) * 16384, bl[l], out, houts[l],
            l == 0 ? 1 : 0);
        h = houts[l];
    }
}